// Round 5
// baseline (270.889 us; speedup 1.0000x reference)
//
#include <hip/hip_runtime.h>
#include <math.h>

// SimpleInfoNCE: N=8192 (2048 groups of 4), D=256, T=0.5.
// normalize -> bf16 hi/lo split (row-major) -> symmetric triangle MFMA GEMM
// 256x256 tiles, 32x32x16 MFMA, 3-buffer counted-vmcnt pipeline -> log/mean.
#define NROW 8192
#define DIM 256
#define NP 32               // 256-row panels
#define NBLK 528            // NP*(NP+1)/2 upper-triangle tiles
#define NT 24               // 3 passes (HiHi,HiLo,LoHi) x 8 steps of K=32

typedef float f32x16 __attribute__((ext_vector_type(16)));
typedef short short8 __attribute__((ext_vector_type(8)));

__device__ __forceinline__ ushort f2bf_rne(float x) {
    unsigned u = __float_as_uint(x);
    unsigned r = (u + 0x7FFFu + ((u >> 16) & 1u)) >> 16;
    return (ushort)r;
}
__device__ __forceinline__ float bf2f(ushort h) {
    return __uint_as_float(((unsigned)h) << 16);
}

// One wave per row: 1/||f||, write normalized bf16 hi/lo ROW-MAJOR (fully
// coalesced 8B/lane stores). Also zeroes the 16K-float sum buffer.
__global__ __launch_bounds__(256) void prep_kernel(const float* __restrict__ f,
                                                   ushort* __restrict__ Hi,
                                                   ushort* __restrict__ Lo,
                                                   float* __restrict__ sums) {
    if (blockIdx.x < 64) sums[blockIdx.x * 256 + threadIdx.x] = 0.0f;
    const int row = blockIdx.x * 4 + (threadIdx.x >> 6);
    const int l   = threadIdx.x & 63;
    float4 v = reinterpret_cast<const float4*>(f + (size_t)row * DIM)[l];
    float ss = v.x * v.x + v.y * v.y + v.z * v.z + v.w * v.w;
#pragma unroll
    for (int m = 32; m; m >>= 1) ss += __shfl_xor(ss, m, 64);
    const float inv = 1.0f / sqrtf(ss);
    float xv[4] = {v.x * inv, v.y * inv, v.z * inv, v.w * inv};
    ushort hv[4], lv[4];
#pragma unroll
    for (int i = 0; i < 4; ++i) {
        hv[i] = f2bf_rne(xv[i]);
        lv[i] = f2bf_rne(xv[i] - bf2f(hv[i]));
    }
    reinterpret_cast<ushort4*>(Hi + (size_t)row * DIM)[l] = make_ushort4(hv[0], hv[1], hv[2], hv[3]);
    reinterpret_cast<ushort4*>(Lo + (size_t)row * DIM)[l] = make_ushort4(lv[0], lv[1], lv[2], lv[3]);
}

__device__ __forceinline__ void gload16(const void* g, void* lp) {
    __builtin_amdgcn_global_load_lds((__attribute__((address_space(1))) void*)g,
                                     (__attribute__((address_space(3))) void*)lp, 16, 0, 0);
}

// 256x256 tile, 8 waves (2x4), wave tile 128x64 = 4x2 frags of 32x32x16.
// LDS per step-buffer: A 16KB + B 16KB; chunk (rb,kh) = 32 rows x 16 k = 1KB,
// lane l holds (row=l&31, kg=l>>5) -> LDS dest linear lane*16B (rule-21 OK),
// global src = row-major 16B-contiguous per lane.
// Pipeline: tile t in buf[t%3]; stage t+2 during t; vmcnt(4) + one barrier.
__global__ __launch_bounds__(512, 2) void infonce_mfma(const ushort* __restrict__ Hi,
                                                       const ushort* __restrict__ Lo,
                                                       float* __restrict__ all_sum,
                                                       float* __restrict__ pos_sum) {
    __shared__ ushort lds[3][16384];   // 3 x 32KB = 96KB

    // XCD swizzle (528 = 8*66, bijective) then unrank -> upper triangle
    const int swz = (blockIdx.x & 7) * 66 + (blockIdx.x >> 3);
    int ti = 0, rem = swz;
    while (rem >= NP - ti) { rem -= NP - ti; ++ti; }
    const int tj = ti + rem;

    const int tid = threadIdx.x;
    const int wid = tid >> 6, l = tid & 63;
    const int wr = wid >> 2, wc = wid & 3;   // wave tile: rows wr*128, cols wc*64
    const int h = l >> 5, c32 = l & 31;
    const int laneoff = (h << 8) + (c32 << 3);                 // ushort offset, == lane*8 ushorts
    const size_t aOff = (size_t)(ti * 256 + wid * 32 + c32) * DIM + h * 8;
    const size_t bOff = (size_t)(tj * 256 + wid * 32 + c32) * DIM + h * 8;

    f32x16 acc[4][2];
#pragma unroll
    for (int m = 0; m < 4; ++m)
#pragma unroll
        for (int n = 0; n < 2; ++n)
#pragma unroll
            for (int e = 0; e < 16; ++e) acc[m][n][e] = 0.0f;

#define STAGE(bufi, t) do {                                                             \
        const int pass_ = (t) >> 3, kb_ = ((t) & 7) * 32;                               \
        const ushort* As_ = (pass_ == 2) ? Lo : Hi;                                     \
        const ushort* Bs_ = (pass_ == 1) ? Lo : Hi;                                     \
        gload16(As_ + aOff + kb_,      &lds[bufi][(wid * 2 + 0) * 512 + laneoff]);      \
        gload16(As_ + aOff + kb_ + 16, &lds[bufi][(wid * 2 + 1) * 512 + laneoff]);      \
        gload16(Bs_ + bOff + kb_,      &lds[bufi][8192 + (wid * 2 + 0) * 512 + laneoff]); \
        gload16(Bs_ + bOff + kb_ + 16, &lds[bufi][8192 + (wid * 2 + 1) * 512 + laneoff]); \
    } while (0)

#define VWAIT(n) asm volatile("s_waitcnt vmcnt(" #n ")" ::: "memory")

#define BODY(t, bR, bS, DOSTG, W) do {                                                  \
        const ushort* bp_ = lds[bR];                                                    \
        short8 a0_[4], b0_[2], a1_[4], b1_[2];                                          \
        _Pragma("unroll") for (int m = 0; m < 4; ++m)                                   \
            a0_[m] = *(const short8*)&bp_[((wr * 4 + m) * 2 + 0) * 512 + laneoff];      \
        _Pragma("unroll") for (int n = 0; n < 2; ++n)                                   \
            b0_[n] = *(const short8*)&bp_[8192 + ((wc * 2 + n) * 2 + 0) * 512 + laneoff]; \
        if (DOSTG) STAGE(bS, (t) + 2);                                                  \
        _Pragma("unroll") for (int m = 0; m < 4; ++m)                                   \
            a1_[m] = *(const short8*)&bp_[((wr * 4 + m) * 2 + 1) * 512 + laneoff];      \
        _Pragma("unroll") for (int n = 0; n < 2; ++n)                                   \
            b1_[n] = *(const short8*)&bp_[8192 + ((wc * 2 + n) * 2 + 1) * 512 + laneoff]; \
        __builtin_amdgcn_s_setprio(1);                                                  \
        _Pragma("unroll") for (int m = 0; m < 4; ++m)                                   \
            _Pragma("unroll") for (int n = 0; n < 2; ++n)                               \
                acc[m][n] = __builtin_amdgcn_mfma_f32_32x32x16_bf16(a0_[m], b0_[n], acc[m][n], 0, 0, 0); \
        _Pragma("unroll") for (int m = 0; m < 4; ++m)                                   \
            _Pragma("unroll") for (int n = 0; n < 2; ++n)                               \
                acc[m][n] = __builtin_amdgcn_mfma_f32_32x32x16_bf16(a1_[m], b1_[n], acc[m][n], 0, 0, 0); \
        __builtin_amdgcn_s_setprio(0);                                                  \
        VWAIT(W);                                                                       \
        __builtin_amdgcn_s_barrier();                                                   \
    } while (0)

    // prologue: stage tiles 0,1; force tile-0 complete; barrier
    STAGE(0, 0);
    STAGE(1, 1);
    VWAIT(4);
    __builtin_amdgcn_s_barrier();

#pragma unroll 1
    for (int tb = 0; tb < 21; tb += 3) {       // t = 0..20 (t=20 stages 22)
        BODY(tb + 0, 0, 2, 1, 4);
        BODY(tb + 1, 1, 0, 1, 4);
        BODY(tb + 2, 2, 1, 1, 4);
    }
    BODY(21, 0, 2, 1, 4);                      // stages 23 -> buf 2; forces 22 done
    BODY(22, 1, 0, 0, 0);                      // forces 23 done
    BODY(23, 2, 0, 0, 0);

    // ---- epilogue: exp + masked sums (C/D: col=lane&31, row=(e&3)+8*(e>>2)+4*(l>>5)) ----
    const int rb0 = ti * 256 + wr * 128;
    const int cb0 = tj * 256 + wc * 64;

    if (ti == tj) {
#pragma unroll
        for (int m = 0; m < 4; ++m)
#pragma unroll
            for (int e = 0; e < 16; ++e) {
                const int row = rb0 + m * 32 + (e & 3) + 8 * (e >> 2) + 4 * h;
                float asum = 0.f, psum = 0.f;
#pragma unroll
                for (int n = 0; n < 2; ++n) {
                    const int col = cb0 + n * 32 + c32;
                    float v = __expf(2.0f * acc[m][n][e]);
                    v = (row == col) ? 0.f : v;
                    asum += v;
                    psum += ((row >> 2) == (col >> 2)) ? v : 0.f;
                }
#pragma unroll
                for (int mk = 1; mk < 32; mk <<= 1) {
                    asum += __shfl_xor(asum, mk, 64);
                    psum += __shfl_xor(psum, mk, 64);
                }
                if (c32 == 0) {
                    atomicAdd(&all_sum[row], asum);
                    atomicAdd(&pos_sum[row], psum);
                }
            }
    } else {
        float cs0 = 0.f, cs1 = 0.f;
#pragma unroll
        for (int m = 0; m < 4; ++m)
#pragma unroll
            for (int e = 0; e < 16; ++e) {
                const int row = rb0 + m * 32 + (e & 3) + 8 * (e >> 2) + 4 * h;
                float v0 = __expf(2.0f * acc[m][0][e]);
                float v1 = __expf(2.0f * acc[m][1][e]);
                cs0 += v0; cs1 += v1;
                float asum = v0 + v1;
#pragma unroll
                for (int mk = 1; mk < 32; mk <<= 1) asum += __shfl_xor(asum, mk, 64);
                if (c32 == 0) atomicAdd(&all_sum[row], asum);
            }
        cs0 += __shfl_xor(cs0, 32, 64);
        cs1 += __shfl_xor(cs1, 32, 64);
        if (h == 0) {
            atomicAdd(&all_sum[cb0 + c32], cs0);
            atomicAdd(&all_sum[cb0 + 32 + c32], cs1);
        }
    }
#undef STAGE
#undef VWAIT
#undef BODY
}

__global__ __launch_bounds__(1024) void loss_kernel(const float* __restrict__ all_sum,
                                                    const float* __restrict__ pos_sum,
                                                    float* __restrict__ out) {
    const int tid = threadIdx.x;
    float s = 0.0f;
#pragma unroll
    for (int r = 0; r < 8; ++r) {
        const int i = tid + r * 1024;
        s += __logf(all_sum[i]) - __logf(pos_sum[i]);
    }
#pragma unroll
    for (int off = 32; off; off >>= 1) s += __shfl_xor(s, off, 64);
    __shared__ float red[16];
    if ((tid & 63) == 0) red[tid >> 6] = s;
    __syncthreads();
    if (tid == 0) {
        float tot = 0.f;
#pragma unroll
        for (int i = 0; i < 16; ++i) tot += red[i];
        out[0] = tot / (float)NROW;
    }
}

extern "C" void kernel_launch(void* const* d_in, const int* in_sizes, int n_in,
                              void* d_out, int out_size, void* d_ws, size_t ws_size,
                              hipStream_t stream) {
    const float* f = (const float*)d_in[0];
    float* out = (float*)d_out;

    float*  all_sum = (float*)d_ws;                    // 8192 f32
    float*  pos_sum = all_sum + NROW;                  // 8192 f32
    ushort* Hi      = (ushort*)(pos_sum + NROW);       // 8192x256 bf16 row-major
    ushort* Lo      = Hi + (size_t)NROW * DIM;         // 8192x256 bf16 row-major

    prep_kernel<<<NROW / 4, 256, 0, stream>>>(f, Hi, Lo, all_sum);
    infonce_mfma<<<NBLK, 512, 0, stream>>>(Hi, Lo, all_sum, pos_sum);
    loss_kernel<<<1, 1024, 0, stream>>>(all_sum, pos_sum, out);
}

// Round 6
// 250.942 us; speedup vs baseline: 1.0795x; 1.0795x over previous
//
#include <hip/hip_runtime.h>
#include <math.h>

// SimpleInfoNCE: N=8192 (2048 groups of 4), D=256, T=0.5.
// normalize -> bf16 hi/lo split (CHUNKED layout) -> symmetric triangle MFMA
// GEMM 256x256 tiles, 32x32x16 MFMA, 3-buffer counted-vmcnt pipeline -> log/mean.
//
// Chunk layout (both global and LDS, rule-21 both-sides-linear):
//   chunk = 32 rows x 16 k = 512 ushorts; lane l holds (row=l&31, k8=l>>5)
//   ushort_idx(row,k) = (row>>5)*8192 + (k>>4)*512 + ((k>>3)&1)*256 + (row&31)*8 + (k&7)
#define NROW 8192
#define DIM 256
#define NP 32               // 256-row panels
#define NBLK 528            // NP*(NP+1)/2 upper-triangle tiles
#define NT 24               // 3 passes (HiHi,HiLo,LoHi) x 8 steps of K=32

typedef float f32x16 __attribute__((ext_vector_type(16)));
typedef short short8 __attribute__((ext_vector_type(8)));

__device__ __forceinline__ ushort f2bf_rne(float x) {
    unsigned u = __float_as_uint(x);
    unsigned r = (u + 0x7FFFu + ((u >> 16) & 1u)) >> 16;
    return (ushort)r;
}
__device__ __forceinline__ float bf2f(ushort h) {
    return __uint_as_float(((unsigned)h) << 16);
}

// 32 rows per block (= one chunk-row). Coalesced float4 row loads, per-wave
// norm, LDS-staged layout transform, fully coalesced chunked stores.
// Also zeroes the 16K-float sum buffer (64 floats per block).
__global__ __launch_bounds__(256) void prep_kernel(const float* __restrict__ f,
                                                   ushort* __restrict__ Hi,
                                                   ushort* __restrict__ Lo,
                                                   float* __restrict__ sums) {
    __shared__ ushort hbuf[8192];
    __shared__ ushort lbuf[8192];
    const int tid = threadIdx.x;
    if (tid < 64) sums[blockIdx.x * 64 + tid] = 0.0f;
    const int w = tid >> 6, l = tid & 63;
    const int r0 = blockIdx.x * 32;
#pragma unroll
    for (int it = 0; it < 8; ++it) {
        const int rl = it * 4 + w;                       // row_local 0..31
        float4 v = reinterpret_cast<const float4*>(f + (size_t)(r0 + rl) * DIM)[l];
        float ss = v.x * v.x + v.y * v.y + v.z * v.z + v.w * v.w;
#pragma unroll
        for (int m = 32; m; m >>= 1) ss += __shfl_xor(ss, m, 64);
        const float inv = 1.0f / sqrtf(ss);
        float xv[4] = {v.x * inv, v.y * inv, v.z * inv, v.w * inv};
        ushort hv[4], lv[4];
#pragma unroll
        for (int i = 0; i < 4; ++i) {
            hv[i] = f2bf_rne(xv[i]);
            lv[i] = f2bf_rne(xv[i] - bf2f(hv[i]));
        }
        // k0 = 4l: chunk_k = l>>2, kh8 = (l>>1)&1, j0 = (l&1)*4
        const int pos = (l >> 2) * 512 + ((l >> 1) & 1) * 256 + rl * 8 + (l & 1) * 4;
        *reinterpret_cast<ushort4*>(&hbuf[pos]) = make_ushort4(hv[0], hv[1], hv[2], hv[3]);
        *reinterpret_cast<ushort4*>(&lbuf[pos]) = make_ushort4(lv[0], lv[1], lv[2], lv[3]);
    }
    __syncthreads();
    const size_t gbase = (size_t)blockIdx.x * 8192;
#pragma unroll
    for (int it = 0; it < 8; ++it) {
        const int o = it * 1024 + tid * 4;
        *reinterpret_cast<ushort4*>(&Hi[gbase + o]) = *reinterpret_cast<const ushort4*>(&hbuf[o]);
        *reinterpret_cast<ushort4*>(&Lo[gbase + o]) = *reinterpret_cast<const ushort4*>(&lbuf[o]);
    }
}

__device__ __forceinline__ void gload16(const void* g, void* lp) {
    __builtin_amdgcn_global_load_lds((__attribute__((address_space(1))) void*)g,
                                     (__attribute__((address_space(3))) void*)lp, 16, 0, 0);
}

// 256x256 tile, 8 waves (2x4), wave tile 128x64 = 4x2 frags of 32x32x16.
// Pipeline: tile t in buf[t%3]; stage t+2 during t; vmcnt(4) + one barrier.
// Stage: per wave 4 x gload16, global src chunk-contiguous (lane*16B), LDS
// dest linear (lane*16B) -> coalesced both sides, conflict-free frag reads.
__global__ __launch_bounds__(512, 2) void infonce_mfma(const ushort* __restrict__ Hi,
                                                       const ushort* __restrict__ Lo,
                                                       float* __restrict__ all_sum,
                                                       float* __restrict__ pos_sum) {
    __shared__ ushort lds[3][16384];   // 3 x 32KB = 96KB

    // XCD swizzle (528 = 8*66, bijective) then unrank -> upper triangle
    const int swz = (blockIdx.x & 7) * 66 + (blockIdx.x >> 3);
    int ti = 0, rem = swz;
    while (rem >= NP - ti) { rem -= NP - ti; ++ti; }
    const int tj = ti + rem;

    const int tid = threadIdx.x;
    const int wid = tid >> 6, l = tid & 63;
    const int wr = wid >> 2, wc = wid & 3;   // wave tile: rows wr*128, cols wc*64
    const int h = l >> 5, c32 = l & 31;
    const int lane8 = l * 8;                 // ushort offset == lane*16B
    const size_t aChunk = (size_t)(ti * 8 + wid) * 8192;   // this wave's A chunk-row
    const size_t bChunk = (size_t)(tj * 8 + wid) * 8192;   // this wave's B chunk-row

    f32x16 acc[4][2];
#pragma unroll
    for (int m = 0; m < 4; ++m)
#pragma unroll
        for (int n = 0; n < 2; ++n)
#pragma unroll
            for (int e = 0; e < 16; ++e) acc[m][n][e] = 0.0f;

#define STAGE(bufi, t) do {                                                             \
        const int pass_ = (t) >> 3;                                                     \
        const int kc_ = ((t) & 7) * 1024;    /* 2 chunks of 512 ushorts per K=32 */     \
        const ushort* As_ = (pass_ == 2) ? Lo : Hi;                                     \
        const ushort* Bs_ = (pass_ == 1) ? Lo : Hi;                                     \
        gload16(As_ + aChunk + kc_ +       lane8, &lds[bufi][(wid * 2 + 0) * 512 + lane8]); \
        gload16(As_ + aChunk + kc_ + 512 + lane8, &lds[bufi][(wid * 2 + 1) * 512 + lane8]); \
        gload16(Bs_ + bChunk + kc_ +       lane8, &lds[bufi][8192 + (wid * 2 + 0) * 512 + lane8]); \
        gload16(Bs_ + bChunk + kc_ + 512 + lane8, &lds[bufi][8192 + (wid * 2 + 1) * 512 + lane8]); \
    } while (0)

#define VWAIT(n) asm volatile("s_waitcnt vmcnt(" #n ")" ::: "memory")

#define BODY(t, bR, bS, DOSTG, W) do {                                                  \
        const ushort* bp_ = lds[bR];                                                    \
        short8 a0_[4], b0_[2], a1_[4], b1_[2];                                          \
        _Pragma("unroll") for (int m = 0; m < 4; ++m)                                   \
            a0_[m] = *(const short8*)&bp_[((wr * 4 + m) * 2 + 0) * 512 + lane8];        \
        _Pragma("unroll") for (int n = 0; n < 2; ++n)                                   \
            b0_[n] = *(const short8*)&bp_[8192 + ((wc * 2 + n) * 2 + 0) * 512 + lane8]; \
        if (DOSTG) STAGE(bS, (t) + 2);                                                  \
        _Pragma("unroll") for (int m = 0; m < 4; ++m)                                   \
            a1_[m] = *(const short8*)&bp_[((wr * 4 + m) * 2 + 1) * 512 + lane8];        \
        _Pragma("unroll") for (int n = 0; n < 2; ++n)                                   \
            b1_[n] = *(const short8*)&bp_[8192 + ((wc * 2 + n) * 2 + 1) * 512 + lane8]; \
        __builtin_amdgcn_s_setprio(1);                                                  \
        _Pragma("unroll") for (int m = 0; m < 4; ++m)                                   \
            _Pragma("unroll") for (int n = 0; n < 2; ++n)                               \
                acc[m][n] = __builtin_amdgcn_mfma_f32_32x32x16_bf16(a0_[m], b0_[n], acc[m][n], 0, 0, 0); \
        _Pragma("unroll") for (int m = 0; m < 4; ++m)                                   \
            _Pragma("unroll") for (int n = 0; n < 2; ++n)                               \
                acc[m][n] = __builtin_amdgcn_mfma_f32_32x32x16_bf16(a1_[m], b1_[n], acc[m][n], 0, 0, 0); \
        __builtin_amdgcn_s_setprio(0);                                                  \
        VWAIT(W);                                                                       \
        __builtin_amdgcn_s_barrier();                                                   \
    } while (0)

    // prologue: stage tiles 0,1; force tile-0 complete; barrier
    STAGE(0, 0);
    STAGE(1, 1);
    VWAIT(4);
    __builtin_amdgcn_s_barrier();

#pragma unroll 1
    for (int tb = 0; tb < 21; tb += 3) {       // t = 0..20 (t=20 stages 22)
        BODY(tb + 0, 0, 2, 1, 4);
        BODY(tb + 1, 1, 0, 1, 4);
        BODY(tb + 2, 2, 1, 1, 4);
    }
    BODY(21, 0, 2, 1, 4);                      // stages 23 -> buf 2; forces 22 done
    BODY(22, 1, 0, 0, 0);                      // forces 23 done
    BODY(23, 2, 0, 0, 0);

    // ---- epilogue: exp + masked sums (C/D: col=lane&31, row=(e&3)+8*(e>>2)+4*(l>>5)) ----
    const int rb0 = ti * 256 + wr * 128;
    const int cb0 = tj * 256 + wc * 64;

    if (ti == tj) {
#pragma unroll
        for (int m = 0; m < 4; ++m)
#pragma unroll
            for (int e = 0; e < 16; ++e) {
                const int row = rb0 + m * 32 + (e & 3) + 8 * (e >> 2) + 4 * h;
                float asum = 0.f, psum = 0.f;
#pragma unroll
                for (int n = 0; n < 2; ++n) {
                    const int col = cb0 + n * 32 + c32;
                    float v = __expf(2.0f * acc[m][n][e]);
                    v = (row == col) ? 0.f : v;
                    asum += v;
                    psum += ((row >> 2) == (col >> 2)) ? v : 0.f;
                }
#pragma unroll
                for (int mk = 1; mk < 32; mk <<= 1) {
                    asum += __shfl_xor(asum, mk, 64);
                    psum += __shfl_xor(psum, mk, 64);
                }
                if (c32 == 0) {
                    atomicAdd(&all_sum[row], asum);
                    atomicAdd(&pos_sum[row], psum);
                }
            }
    } else {
        float cs0 = 0.f, cs1 = 0.f;
#pragma unroll
        for (int m = 0; m < 4; ++m)
#pragma unroll
            for (int e = 0; e < 16; ++e) {
                const int row = rb0 + m * 32 + (e & 3) + 8 * (e >> 2) + 4 * h;
                float v0 = __expf(2.0f * acc[m][0][e]);
                float v1 = __expf(2.0f * acc[m][1][e]);
                cs0 += v0; cs1 += v1;
                float asum = v0 + v1;
#pragma unroll
                for (int mk = 1; mk < 32; mk <<= 1) asum += __shfl_xor(asum, mk, 64);
                if (c32 == 0) atomicAdd(&all_sum[row], asum);
            }
        cs0 += __shfl_xor(cs0, 32, 64);
        cs1 += __shfl_xor(cs1, 32, 64);
        if (h == 0) {
            atomicAdd(&all_sum[cb0 + c32], cs0);
            atomicAdd(&all_sum[cb0 + 32 + c32], cs1);
        }
    }
#undef STAGE
#undef VWAIT
#undef BODY
}

__global__ __launch_bounds__(1024) void loss_kernel(const float* __restrict__ all_sum,
                                                    const float* __restrict__ pos_sum,
                                                    float* __restrict__ out) {
    const int tid = threadIdx.x;
    float s = 0.0f;
#pragma unroll
    for (int r = 0; r < 8; ++r) {
        const int i = tid + r * 1024;
        s += __logf(all_sum[i]) - __logf(pos_sum[i]);
    }
#pragma unroll
    for (int off = 32; off; off >>= 1) s += __shfl_xor(s, off, 64);
    __shared__ float red[16];
    if ((tid & 63) == 0) red[tid >> 6] = s;
    __syncthreads();
    if (tid == 0) {
        float tot = 0.f;
#pragma unroll
        for (int i = 0; i < 16; ++i) tot += red[i];
        out[0] = tot / (float)NROW;
    }
}

extern "C" void kernel_launch(void* const* d_in, const int* in_sizes, int n_in,
                              void* d_out, int out_size, void* d_ws, size_t ws_size,
                              hipStream_t stream) {
    const float* f = (const float*)d_in[0];
    float* out = (float*)d_out;

    float*  all_sum = (float*)d_ws;                    // 8192 f32
    float*  pos_sum = all_sum + NROW;                  // 8192 f32
    ushort* Hi      = (ushort*)(pos_sum + NROW);       // 8192x256 bf16, chunked
    ushort* Lo      = Hi + (size_t)NROW * DIM;         // 8192x256 bf16, chunked

    prep_kernel<<<NROW / 32, 256, 0, stream>>>(f, Hi, Lo, all_sum);
    infonce_mfma<<<NBLK, 512, 0, stream>>>(Hi, Lo, all_sum, pos_sum);
    loss_kernel<<<1, 1024, 0, stream>>>(all_sum, pos_sum, out);
}